// Round 1
// baseline (325.627 us; speedup 1.0000x reference)
//
#include <hip/hip_runtime.h>
#include <math.h>

// ---------------------------------------------------------------------------
// CSPN_Propagate — MI355X HIP implementation.
//
// Key analysis of the reference:
//  * masked medians / scale / blur_depth_o are DEAD (rgbd[:,0:1] == rgb ch0).
//  * gt is only used via center_crop(gt_where_filtered, 96, 192).
//  * the i==0 sparse substitution inside _cspn is an exact no-op.
//  * dep_last is only needed through dep_fusion ("raw"); each stage's
//    finalize directly produces the next stage's raw.
// Stage sizes (B=16): 96x192 -> 128x256 -> 160x320 -> 192x384 (centered).
// ---------------------------------------------------------------------------

#define B 16
#define FH 256
#define FW 512

// ----------------------------- prep: raw0 ----------------------------------
// raw0[b,y,x] over 96x192 crop (offset 80,160):
//   s = gt/blur ; dl = (s>1.2 || s<0.8) ? 0 : gt ; raw = dl>0 ? dl : rgb0
__global__ __launch_bounds__(256) void prep_raw0_kernel(
    const float* __restrict__ gt, const float* __restrict__ blur,
    const float* __restrict__ rgb, float* __restrict__ raw) {
  int idx = blockIdx.x * blockDim.x + threadIdx.x;
  const int h = 96, w = 192, total = B * h * w;
  if (idx >= total) return;
  int x = idx % w;
  int t = idx / w;
  int y = t % h;
  int b = t / h;
  int gy = 80 + y, gx = 160 + x;
  size_t g = (size_t)b * FH * FW + (size_t)gy * FW + gx;
  float gv = gt[g];
  float bv = blur[g];
  float s = gv / bv;
  float dl = (s > 1.2f || s < 0.8f) ? 0.0f : gv;
  float dep = rgb[((size_t)b * 3) * FH * FW + (size_t)gy * FW + gx];
  raw[idx] = (dl > 0.0f) ? dl : dep;
}

// --------------------------- conv block + ELU -------------------------------
// guidance[b,o,y,x] = elu( sum_{ci,ky,kx} featc_reflect[ci,y+ky-1,x+kx-1] *
//                          w[o,ci,ky,kx] + bias[o] )
// featc = features center crop (hs,ws), reflect pad 1 within the crop.
__global__ __launch_bounds__(256) void conv_guid_kernel(
    const float* __restrict__ feat, const float* __restrict__ wgt,
    const float* __restrict__ bias, float* __restrict__ guid,
    int h, int w, int hs, int ws) {
  int idx = blockIdx.x * blockDim.x + threadIdx.x;
  int total = B * h * w;
  if (idx >= total) return;
  int x = idx % w;
  int t = idx / w;
  int y = t % h;
  int b = t / h;

  int ry[3], rx[3];
#pragma unroll
  for (int k = 0; k < 3; ++k) {
    int cy = y + k - 1;
    cy = (cy < 0) ? 1 : ((cy >= h) ? (h - 2) : cy);
    ry[k] = hs + cy;
    int cx = x + k - 1;
    cx = (cx < 0) ? 1 : ((cx >= w) ? (w - 2) : cx);
    rx[k] = ws + cx;
  }

  float acc[8];
#pragma unroll
  for (int o = 0; o < 8; ++o) acc[o] = bias[o];

  const float* fb = feat + (size_t)b * 16 * FH * FW;
  for (int ci = 0; ci < 16; ++ci) {
    const float* fc = fb + (size_t)ci * FH * FW;
#pragma unroll
    for (int ky = 0; ky < 3; ++ky) {
      const float* frow = fc + (size_t)ry[ky] * FW;
#pragma unroll
      for (int kx = 0; kx < 3; ++kx) {
        float v = frow[rx[kx]];
        // weight index is wave-uniform -> scalar (s_load) path
#pragma unroll
        for (int o = 0; o < 8; ++o)
          acc[o] = fmaf(v, wgt[((o * 16 + ci) * 3 + ky) * 3 + kx], acc[o]);
      }
    }
  }

  size_t hw = (size_t)h * w;
  size_t base = (size_t)b * 8 * hw + (size_t)y * w + x;
#pragma unroll
  for (int o = 0; o < 8; ++o) {
    float v = acc[o];
    v = (v > 0.0f) ? v : expm1f(v);
    guid[base + (size_t)o * hw] = v;
  }
}

// --------------------------- CSPN iteration --------------------------------
// next(y,x) = (1 - sum_k g_k / A) * raw(y,x) + (sum_k g_k * prev(n_k)) / A
// where g_k = guid[k] at neighbor n_k, A = sum_k |g_k| (OOB -> 0).
__global__ __launch_bounds__(256) void cspn_iter_kernel(
    const float* __restrict__ guid, const float* __restrict__ raw,
    const float* __restrict__ prev, float* __restrict__ nxt, int h, int w) {
  int idx = blockIdx.x * blockDim.x + threadIdx.x;
  int total = B * h * w;
  if (idx >= total) return;
  int x = idx % w;
  int t = idx / w;
  int y = t % h;
  int b = t / h;

  const int dy[8] = {1, 1, 1, 0, 0, -1, -1, -1};
  const int dx[8] = {1, 0, -1, 1, -1, 1, 0, -1};

  size_t hw = (size_t)h * w;
  const float* gb = guid + (size_t)b * 8 * hw;
  const float* pb = prev + (size_t)b * hw;

  float wsum = 0.0f, asum = 0.0f, nsum = 0.0f;
#pragma unroll
  for (int k = 0; k < 8; ++k) {
    int ny = y + dy[k];
    int nx = x + dx[k];
    if (ny >= 0 && ny < h && nx >= 0 && nx < w) {
      float g = gb[(size_t)k * hw + (size_t)ny * w + nx];
      wsum += g;
      asum += fabsf(g);
      nsum += g * pb[(size_t)ny * w + nx];
    }
  }
  float inv = 1.0f / asum;
  size_t o = (size_t)b * hw + (size_t)y * w + x;
  nxt[o] = (1.0f - wsum * inv) * raw[o] + nsum * inv;
}

// ------------------- finalize: clip + pad + fuse -> next raw ----------------
// rawn over (h2,w2): interior gets clip(res,0,1); raw = dl>0 ? dl : rgb0crop2
__global__ __launch_bounds__(256) void finalize_next_raw_kernel(
    const float* __restrict__ res, const float* __restrict__ rgb,
    float* __restrict__ rawn, int h, int w, int h2, int w2, int hs2, int ws2) {
  int idx = blockIdx.x * blockDim.x + threadIdx.x;
  int total = B * h2 * w2;
  if (idx >= total) return;
  int x2 = idx % w2;
  int t = idx / w2;
  int y2 = t % h2;
  int b = t / h2;
  int ph = (h2 - h) / 2, pw = (w2 - w) / 2;
  int y = y2 - ph, x = x2 - pw;
  float dl = 0.0f;
  if (y >= 0 && y < h && x >= 0 && x < w) {
    float v = res[(size_t)b * h * w + (size_t)y * w + x];
    dl = fminf(fmaxf(v, 0.0f), 1.0f);
  }
  float dep =
      rgb[((size_t)b * 3) * FH * FW + (size_t)(hs2 + y2) * FW + (ws2 + x2)];
  rawn[idx] = (dl > 0.0f) ? dl : dep;
}

// ------------------------- final output (stage 3) ---------------------------
__global__ __launch_bounds__(256) void write_out_kernel(
    const float* __restrict__ res, float* __restrict__ out, int n) {
  int idx = blockIdx.x * blockDim.x + threadIdx.x;
  if (idx >= n) return;
  float v = res[idx];
  out[idx] = fminf(fmaxf(v, 0.0f), 1.0f);
}

// ---------------------------------------------------------------------------
extern "C" void kernel_launch(void* const* d_in, const int* in_sizes, int n_in,
                              void* d_out, int out_size, void* d_ws,
                              size_t ws_size, hipStream_t stream) {
  const float* feat = (const float*)d_in[0];
  const float* blur = (const float*)d_in[1];
  const float* gt = (const float*)d_in[2];
  const float* rgb = (const float*)d_in[3];
  // d_in[4] = stage (arange(4) per setup_inputs; order hardcoded)
  const float* W[4] = {(const float*)d_in[5], (const float*)d_in[7],
                       (const float*)d_in[9], (const float*)d_in[11]};
  const float* Bs[4] = {(const float*)d_in[6], (const float*)d_in[8],
                        (const float*)d_in[10], (const float*)d_in[12]};
  float* out = (float*)d_out;

  // workspace layout (floats)
  float* GUID = (float*)d_ws;                  // 16*8*192*384 = 9,437,184
  float* RAW = GUID + (size_t)B * 8 * 192 * 384;  // 1,179,648 each below
  float* R1 = RAW + (size_t)B * 192 * 384;
  float* R2 = R1 + (size_t)B * 192 * 384;

  const int CH[4] = {96, 128, 160, 192};
  const int CW[4] = {192, 256, 320, 384};

  {
    int n = B * 96 * 192;
    prep_raw0_kernel<<<(n + 255) / 256, 256, 0, stream>>>(gt, blur, rgb, RAW);
  }

  for (int i = 0; i < 4; ++i) {
    int h = CH[i], w = CW[i];
    int hs = (FH - h) / 2, ws = (FW - w) / 2;
    int n = B * h * w;
    int nb = (n + 255) / 256;

    conv_guid_kernel<<<nb, 256, 0, stream>>>(feat, W[i], Bs[i], GUID, h, w, hs,
                                             ws);
    cspn_iter_kernel<<<nb, 256, 0, stream>>>(GUID, RAW, RAW, R1, h, w);
    cspn_iter_kernel<<<nb, 256, 0, stream>>>(GUID, RAW, R1, R2, h, w);
    cspn_iter_kernel<<<nb, 256, 0, stream>>>(GUID, RAW, R2, R1, h, w);

    if (i < 3) {
      int h2 = CH[i + 1], w2 = CW[i + 1];
      int hs2 = (FH - h2) / 2, ws2 = (FW - w2) / 2;
      int n2 = B * h2 * w2;
      finalize_next_raw_kernel<<<(n2 + 255) / 256, 256, 0, stream>>>(
          R1, rgb, RAW, h, w, h2, w2, hs2, ws2);
    } else {
      write_out_kernel<<<(n + 255) / 256, 256, 0, stream>>>(R1, out, n);
    }
  }
}